// Round 5
// baseline (148.495 us; speedup 1.0000x reference)
//
#include <hip/hip_runtime.h>

#define N_GAUSS 16384
#define SPLIT   128
#define GPS     (N_GAUSS / SPLIT)   // 128 gaussians per block slice
#define TILE    64
#define NPIX    (TILE * TILE)       // 4096 pixels per image
#define PPT     2                   // pixels per thread
#define EPS     1e-5f
#define LOG2E   1.44269504088896340736f

// Fully fused: per-block gaussian precompute -> LDS, then per-pixel loop.
// Packed per gaussian: A=(mx,my,mz,sg), B=(r,g,b,e0) with
//   kg2 = -0.5*log2e/(sigma^2+eps), sg = sqrt(-kg2), e0 = kg2*|m-o|^2
// Per-pixel rays pre-scaled by sp = sqrt(-(|d|^2-2)) so that
//   arg = e0 + (t*sg*sp)^2   (note: +, since kg2*dd2 > 0)
__global__ __launch_bounds__(256, 8) void render_kernel(
        const float* __restrict__ means,
        const float* __restrict__ covs,
        const float* __restrict__ colors,
        const float* __restrict__ intr,
        const float* __restrict__ extr,
        const int*   __restrict__ img_ids,
        float*       __restrict__ acc) {   // [n_imgs*NPIX][4] = {w,r,g,b}
    __shared__ float4 sA[GPS];
    __shared__ float4 sB[GPS];

    const int tid   = threadIdx.x;
    const int split = blockIdx.y;
    const int img   = blockIdx.z;

    const int cam = img_ids[img];
    const float* E = extr + 16 * cam;
    const float ox = E[3], oy = E[7], oz = E[11];

    if (tid < GPS) {
        const int g = split * GPS + tid;
        const float mx = means[3 * g + 0];
        const float my = means[3 * g + 1];
        const float mz = means[3 * g + 2];
        const float* c = covs + 9 * g;
        const float s2  = (c[0] + c[4] + c[8]) * (1.0f / 3.0f);
        const float sig = sqrtf(s2);                // match reference rounding
        const float kg2 = -0.5f * LOG2E / (sig * sig + EPS);
        const float sg  = sqrtf(-kg2);
        const float ux = mx - ox, uy = my - oy, uz = mz - oz;
        const float e0 = kg2 * (ux * ux + uy * uy + uz * uz);
        sA[tid] = make_float4(mx, my, mz, sg);
        sB[tid] = make_float4(colors[3 * g + 0], colors[3 * g + 1],
                              colors[3 * g + 2], e0);
    }

    const float* I = intr + 4 * cam;
    const float fx = I[0], fy = I[1], cx = I[2], cy = I[3];

    float rdx[PPT], rdy[PPT], rdz[PPT], mods[PPT];
    int pix[PPT];
    #pragma unroll
    for (int p = 0; p < PPT; p++) {
        pix[p] = blockIdx.x * 256 + tid + p * (NPIX / PPT);
        const int row = pix[p] >> 6;
        const int col = pix[p] & 63;
        const float d0 = ((float)col - cx) / fx;
        const float d1 = -(((float)row) - cy) / fy;
        const float d2 = -1.0f;
        const float x = d0 * E[0] + d1 * E[1] + d2 * E[2];
        const float y = d0 * E[4] + d1 * E[5] + d2 * E[6];
        const float z = d0 * E[8] + d1 * E[9] + d2 * E[10];
        const float dd2 = x * x + y * y + z * z - 2.0f;   // < 0 for this setup
        const float sp  = sqrtf(-dd2);
        rdx[p] = x * sp; rdy[p] = y * sp; rdz[p] = z * sp;
        mods[p] = -(ox * x + oy * y + oz * z) * sp;
    }

    __syncthreads();

    float w0 = 0.f, r0 = 0.f, g0 = 0.f, b0 = 0.f;
    float w1 = 0.f, r1 = 0.f, g1 = 0.f, b1 = 0.f;
    #pragma unroll 4
    for (int g = 0; g < GPS; g++) {
        const float4 a = sA[g];
        const float4 b = sB[g];
        const float t0 = fmaf(a.x, rdx[0], fmaf(a.y, rdy[0], fmaf(a.z, rdz[0], mods[0])));
        const float t1 = fmaf(a.x, rdx[1], fmaf(a.y, rdy[1], fmaf(a.z, rdz[1], mods[1])));
        const float u0 = t0 * a.w;
        const float u1 = t1 * a.w;
        const float e_0 = __builtin_amdgcn_exp2f(fmaf(u0, u0, b.w));
        const float e_1 = __builtin_amdgcn_exp2f(fmaf(u1, u1, b.w));
        w0 += e_0; r0 = fmaf(e_0, b.x, r0); g0 = fmaf(e_0, b.y, g0); b0 = fmaf(e_0, b.z, b0);
        w1 += e_1; r1 = fmaf(e_1, b.x, r1); g1 = fmaf(e_1, b.y, g1); b1 = fmaf(e_1, b.z, b1);
    }

    float* A0 = acc + 4 * (img * NPIX + pix[0]);
    atomicAdd(A0 + 0, w0); atomicAdd(A0 + 1, r0);
    atomicAdd(A0 + 2, g0); atomicAdd(A0 + 3, b0);
    float* A1 = acc + 4 * (img * NPIX + pix[1]);
    atomicAdd(A1 + 0, w1); atomicAdd(A1 + 1, r1);
    atomicAdd(A1 + 2, g1); atomicAdd(A1 + 3, b1);
}

__global__ void finalize_kernel(const float4* __restrict__ acc,
                                float* __restrict__ out,
                                int n_imgs) {
    const int idx = blockIdx.x * blockDim.x + threadIdx.x;
    if (idx >= n_imgs * NPIX) return;
    const float4 p = acc[idx];
    const float inv = 1.0f / (p.x + EPS);
    const int img = idx >> 12;
    const int pix = idx & (NPIX - 1);
    out[(img * 3 + 0) * NPIX + pix] = p.y * inv;
    out[(img * 3 + 1) * NPIX + pix] = p.z * inv;
    out[(img * 3 + 2) * NPIX + pix] = p.w * inv;
}

extern "C" void kernel_launch(void* const* d_in, const int* in_sizes, int n_in,
                              void* d_out, int out_size, void* d_ws, size_t ws_size,
                              hipStream_t stream) {
    const float* means   = (const float*)d_in[0];
    const float* covs    = (const float*)d_in[1];
    const float* colors  = (const float*)d_in[2];
    const float* intr    = (const float*)d_in[3];
    const float* extr    = (const float*)d_in[4];
    const int*   img_ids = (const int*)d_in[5];
    float* out = (float*)d_out;
    const int n_imgs = in_sizes[5];

    float* acc = (float*)d_ws;   // n_imgs * NPIX * 4 floats (128 KB @ n_imgs=2)
    hipMemsetAsync(acc, 0, (size_t)n_imgs * NPIX * 4 * sizeof(float), stream);

    dim3 grid(NPIX / (256 * PPT), SPLIT, n_imgs);
    render_kernel<<<grid, 256, 0, stream>>>(means, covs, colors, intr, extr,
                                            img_ids, acc);

    const int total = n_imgs * NPIX;
    finalize_kernel<<<(total + 255) / 256, 256, 0, stream>>>(
        (const float4*)acc, out, n_imgs);
}

// Round 6
// 106.295 us; speedup vs baseline: 1.3970x; 1.3970x over previous
//
#include <hip/hip_runtime.h>

#define N_GAUSS 16384
#define SPLIT   128
#define GPS     (N_GAUSS / SPLIT)   // 128 gaussians per block slice
#define TILE    64
#define NPIX    (TILE * TILE)       // 4096 pixels per image
#define PPT     2                   // pixels per thread
#define EPS     1e-5f
#define LOG2E   1.44269504088896340736f

// Fully fused: per-block gaussian precompute -> LDS, then per-pixel loop.
// Packed per gaussian: A=(mx,my,mz,sg), B=(r,g,b,e0) with
//   kg2 = -0.5*log2e/(sigma^2+eps), sg = sqrt(-kg2), e0 = kg2*|m-o|^2
// Per-pixel rays pre-scaled by sp = sqrt(-(|d|^2-2)) so that
//   arg = e0 + (t*sg*sp)^2   (+, since kg2*dd2 > 0)
__global__ __launch_bounds__(256, 8) void render_kernel(
        const float* __restrict__ means,
        const float* __restrict__ covs,
        const float* __restrict__ colors,
        const float* __restrict__ intr,
        const float* __restrict__ extr,
        const int*   __restrict__ img_ids,
        float4*      __restrict__ partial) {  // [SPLIT][n_imgs*NPIX]
    __shared__ float4 sA[GPS];
    __shared__ float4 sB[GPS];

    const int tid   = threadIdx.x;
    const int split = blockIdx.y;
    const int img   = blockIdx.z;
    const int n_imgs = gridDim.z;

    const int cam = img_ids[img];
    const float* E = extr + 16 * cam;
    const float ox = E[3], oy = E[7], oz = E[11];

    if (tid < GPS) {
        const int g = split * GPS + tid;
        const float mx = means[3 * g + 0];
        const float my = means[3 * g + 1];
        const float mz = means[3 * g + 2];
        const float* c = covs + 9 * g;
        const float s2  = (c[0] + c[4] + c[8]) * (1.0f / 3.0f);
        const float sig = sqrtf(s2);                // match reference rounding
        const float kg2 = -0.5f * LOG2E / (sig * sig + EPS);
        const float sg  = sqrtf(-kg2);
        const float ux = mx - ox, uy = my - oy, uz = mz - oz;
        const float e0 = kg2 * (ux * ux + uy * uy + uz * uz);
        sA[tid] = make_float4(mx, my, mz, sg);
        sB[tid] = make_float4(colors[3 * g + 0], colors[3 * g + 1],
                              colors[3 * g + 2], e0);
    }

    const float* I = intr + 4 * cam;
    const float fx = I[0], fy = I[1], cx = I[2], cy = I[3];

    float rdx[PPT], rdy[PPT], rdz[PPT], mods[PPT];
    int pix[PPT];
    #pragma unroll
    for (int p = 0; p < PPT; p++) {
        pix[p] = blockIdx.x * 256 + tid + p * (NPIX / PPT);
        const int row = pix[p] >> 6;
        const int col = pix[p] & 63;
        const float d0 = ((float)col - cx) / fx;
        const float d1 = -(((float)row) - cy) / fy;
        const float d2 = -1.0f;
        const float x = d0 * E[0] + d1 * E[1] + d2 * E[2];
        const float y = d0 * E[4] + d1 * E[5] + d2 * E[6];
        const float z = d0 * E[8] + d1 * E[9] + d2 * E[10];
        const float dd2 = x * x + y * y + z * z - 2.0f;   // < 0 for this setup
        const float sp  = sqrtf(-dd2);
        rdx[p] = x * sp; rdy[p] = y * sp; rdz[p] = z * sp;
        mods[p] = -(ox * x + oy * y + oz * z) * sp;
    }

    __syncthreads();

    float w0 = 0.f, r0 = 0.f, g0 = 0.f, b0 = 0.f;
    float w1 = 0.f, r1 = 0.f, g1 = 0.f, b1 = 0.f;
    #pragma unroll 4
    for (int g = 0; g < GPS; g++) {
        const float4 a = sA[g];
        const float4 b = sB[g];
        const float t0 = fmaf(a.x, rdx[0], fmaf(a.y, rdy[0], fmaf(a.z, rdz[0], mods[0])));
        const float t1 = fmaf(a.x, rdx[1], fmaf(a.y, rdy[1], fmaf(a.z, rdz[1], mods[1])));
        const float u0 = t0 * a.w;
        const float u1 = t1 * a.w;
        const float e_0 = __builtin_amdgcn_exp2f(fmaf(u0, u0, b.w));
        const float e_1 = __builtin_amdgcn_exp2f(fmaf(u1, u1, b.w));
        w0 += e_0; r0 = fmaf(e_0, b.x, r0); g0 = fmaf(e_0, b.y, g0); b0 = fmaf(e_0, b.z, b0);
        w1 += e_1; r1 = fmaf(e_1, b.x, r1); g1 = fmaf(e_1, b.y, g1); b1 = fmaf(e_1, b.z, b1);
    }

    const int stride = n_imgs * NPIX;
    float4* P = partial + (size_t)split * stride + img * NPIX;
    P[pix[0]] = make_float4(w0, r0, g0, b0);
    P[pix[1]] = make_float4(w1, r1, g1, b1);
}

__global__ void reduce_kernel(const float4* __restrict__ partial,
                              float* __restrict__ out,
                              int n_imgs) {
    const int idx = blockIdx.x * blockDim.x + threadIdx.x;
    const int total = n_imgs * NPIX;
    if (idx >= total) return;
    float w = 0.0f, r = 0.0f, g = 0.0f, b = 0.0f;
    #pragma unroll 8
    for (int s = 0; s < SPLIT; s++) {
        const float4 p = partial[(size_t)s * total + idx];
        w += p.x; r += p.y; g += p.z; b += p.w;
    }
    const float inv = 1.0f / (w + EPS);
    const int img = idx >> 12;        // / NPIX
    const int pix = idx & (NPIX - 1);
    out[(img * 3 + 0) * NPIX + pix] = r * inv;
    out[(img * 3 + 1) * NPIX + pix] = g * inv;
    out[(img * 3 + 2) * NPIX + pix] = b * inv;
}

extern "C" void kernel_launch(void* const* d_in, const int* in_sizes, int n_in,
                              void* d_out, int out_size, void* d_ws, size_t ws_size,
                              hipStream_t stream) {
    const float* means   = (const float*)d_in[0];
    const float* covs    = (const float*)d_in[1];
    const float* colors  = (const float*)d_in[2];
    const float* intr    = (const float*)d_in[3];
    const float* extr    = (const float*)d_in[4];
    const int*   img_ids = (const int*)d_in[5];
    float* out = (float*)d_out;
    const int n_imgs = in_sizes[5];

    float4* partial = (float4*)d_ws;   // SPLIT * n_imgs * NPIX float4s

    dim3 grid(NPIX / (256 * PPT), SPLIT, n_imgs);
    render_kernel<<<grid, 256, 0, stream>>>(means, covs, colors, intr, extr,
                                            img_ids, partial);

    const int total = n_imgs * NPIX;
    reduce_kernel<<<(total + 255) / 256, 256, 0, stream>>>(partial, out, n_imgs);
}

// Round 7
// 104.198 us; speedup vs baseline: 1.4251x; 1.0201x over previous
//
#include <hip/hip_runtime.h>

#define N_GAUSS 16384
#define SPLIT   128
#define GPS     (N_GAUSS / SPLIT)   // 128 gaussians per block slice
#define TILE    64
#define NPIX    (TILE * TILE)       // 4096 pixels per image
#define PPT     4                   // pixels per thread (2 packed pairs)
#define EPS     1e-5f
#define LOG2E   1.44269504088896340736f

typedef float v2f __attribute__((ext_vector_type(2)));

// Fully fused: per-block gaussian precompute -> LDS, then per-pixel loop.
// Packed per gaussian: A=(mx,my,mz,sg), B=(r,g,b,e0) with
//   kg2 = -0.5*log2e/(sigma^2+eps), sg = sqrt(-kg2), e0 = kg2*|m-o|^2
// Per-pixel rays pre-scaled by sp = sqrt(-(|d|^2-2)) so that
//   arg = e0 + (t*sg)^2  (exp2 domain). Pixel pairs packed as v2f so the
//   backend can emit v_pk_fma_f32 / v_pk_mul_f32 (double-rate fp32).
__global__ __launch_bounds__(256, 4) void render_kernel(
        const float* __restrict__ means,
        const float* __restrict__ covs,
        const float* __restrict__ colors,
        const float* __restrict__ intr,
        const float* __restrict__ extr,
        const int*   __restrict__ img_ids,
        float4*      __restrict__ partial) {  // [SPLIT][n_imgs*NPIX]
    __shared__ float4 sA[GPS];
    __shared__ float4 sB[GPS];

    const int tid   = threadIdx.x;
    const int split = blockIdx.y;
    const int img   = blockIdx.z;
    const int n_imgs = gridDim.z;

    const int cam = img_ids[img];
    const float* E = extr + 16 * cam;
    const float ox = E[3], oy = E[7], oz = E[11];

    if (tid < GPS) {
        const int g = split * GPS + tid;
        const float mx = means[3 * g + 0];
        const float my = means[3 * g + 1];
        const float mz = means[3 * g + 2];
        const float* c = covs + 9 * g;
        const float s2  = (c[0] + c[4] + c[8]) * (1.0f / 3.0f);
        const float sig = sqrtf(s2);                // match reference rounding
        const float kg2 = -0.5f * LOG2E / (sig * sig + EPS);
        const float sg  = sqrtf(-kg2);
        const float ux = mx - ox, uy = my - oy, uz = mz - oz;
        const float e0 = kg2 * (ux * ux + uy * uy + uz * uz);
        sA[tid] = make_float4(mx, my, mz, sg);
        sB[tid] = make_float4(colors[3 * g + 0], colors[3 * g + 1],
                              colors[3 * g + 2], e0);
    }

    const float* I = intr + 4 * cam;
    const float fx = I[0], fy = I[1], cx = I[2], cy = I[3];

    // 4 pixels per thread as 2 packed pairs
    v2f rx[2], ry[2], rz[2], md[2];
    int pix[PPT];
    #pragma unroll
    for (int p = 0; p < PPT; p++) {
        pix[p] = blockIdx.x * 256 + tid + p * (NPIX / PPT);
        const int row = pix[p] >> 6;
        const int col = pix[p] & 63;
        const float d0 = ((float)col - cx) / fx;
        const float d1 = -(((float)row) - cy) / fy;
        const float d2 = -1.0f;
        const float x = d0 * E[0] + d1 * E[1] + d2 * E[2];
        const float y = d0 * E[4] + d1 * E[5] + d2 * E[6];
        const float z = d0 * E[8] + d1 * E[9] + d2 * E[10];
        const float dd2 = x * x + y * y + z * z - 2.0f;   // < 0 for this setup
        const float sp  = sqrtf(-dd2);
        rx[p >> 1][p & 1] = x * sp;
        ry[p >> 1][p & 1] = y * sp;
        rz[p >> 1][p & 1] = z * sp;
        md[p >> 1][p & 1] = -(ox * x + oy * y + oz * z) * sp;
    }

    __syncthreads();

    v2f wv[2] = {{0.f, 0.f}, {0.f, 0.f}};
    v2f rv[2] = {{0.f, 0.f}, {0.f, 0.f}};
    v2f gv[2] = {{0.f, 0.f}, {0.f, 0.f}};
    v2f bv[2] = {{0.f, 0.f}, {0.f, 0.f}};

    #pragma unroll 4
    for (int g = 0; g < GPS; g++) {
        const float4 a = sA[g];
        const float4 b = sB[g];
        const v2f ax = {a.x, a.x}, ay = {a.y, a.y}, az = {a.z, a.z};
        const v2f sgv = {a.w, a.w};
        const v2f e0v = {b.w, b.w};
        const v2f bxx = {b.x, b.x}, byy = {b.y, b.y}, bzz = {b.z, b.z};
        #pragma unroll
        for (int h = 0; h < 2; h++) {
            const v2f t = __builtin_elementwise_fma(ax, rx[h],
                          __builtin_elementwise_fma(ay, ry[h],
                          __builtin_elementwise_fma(az, rz[h], md[h])));
            const v2f u = t * sgv;
            const v2f arg = __builtin_elementwise_fma(u, u, e0v);
            v2f e;
            e.x = __builtin_amdgcn_exp2f(arg.x);
            e.y = __builtin_amdgcn_exp2f(arg.y);
            wv[h] += e;
            rv[h] = __builtin_elementwise_fma(e, bxx, rv[h]);
            gv[h] = __builtin_elementwise_fma(e, byy, gv[h]);
            bv[h] = __builtin_elementwise_fma(e, bzz, bv[h]);
        }
    }

    const int stride = n_imgs * NPIX;
    float4* P = partial + (size_t)split * stride + img * NPIX;
    #pragma unroll
    for (int p = 0; p < PPT; p++) {
        const int h = p >> 1, l = p & 1;
        P[pix[p]] = make_float4(wv[h][l], rv[h][l], gv[h][l], bv[h][l]);
    }
}

__global__ void reduce_kernel(const float4* __restrict__ partial,
                              float* __restrict__ out,
                              int n_imgs) {
    const int idx = blockIdx.x * blockDim.x + threadIdx.x;
    const int total = n_imgs * NPIX;
    if (idx >= total) return;
    float w = 0.0f, r = 0.0f, g = 0.0f, b = 0.0f;
    #pragma unroll 8
    for (int s = 0; s < SPLIT; s++) {
        const float4 p = partial[(size_t)s * total + idx];
        w += p.x; r += p.y; g += p.z; b += p.w;
    }
    const float inv = 1.0f / (w + EPS);
    const int img = idx >> 12;        // / NPIX
    const int pix = idx & (NPIX - 1);
    out[(img * 3 + 0) * NPIX + pix] = r * inv;
    out[(img * 3 + 1) * NPIX + pix] = g * inv;
    out[(img * 3 + 2) * NPIX + pix] = b * inv;
}

extern "C" void kernel_launch(void* const* d_in, const int* in_sizes, int n_in,
                              void* d_out, int out_size, void* d_ws, size_t ws_size,
                              hipStream_t stream) {
    const float* means   = (const float*)d_in[0];
    const float* covs    = (const float*)d_in[1];
    const float* colors  = (const float*)d_in[2];
    const float* intr    = (const float*)d_in[3];
    const float* extr    = (const float*)d_in[4];
    const int*   img_ids = (const int*)d_in[5];
    float* out = (float*)d_out;
    const int n_imgs = in_sizes[5];

    float4* partial = (float4*)d_ws;   // SPLIT * n_imgs * NPIX float4s

    dim3 grid(NPIX / (256 * PPT), SPLIT, n_imgs);
    render_kernel<<<grid, 256, 0, stream>>>(means, covs, colors, intr, extr,
                                            img_ids, partial);

    const int total = n_imgs * NPIX;
    reduce_kernel<<<(total + 255) / 256, 256, 0, stream>>>(partial, out, n_imgs);
}

// Round 8
// 103.272 us; speedup vs baseline: 1.4379x; 1.0090x over previous
//
#include <hip/hip_runtime.h>

#define N_GAUSS 16384
#define SPLIT   128
#define GPS     (N_GAUSS / SPLIT)   // 128 gaussians per block slice
#define TILE    64
#define NPIX    (TILE * TILE)       // 4096 pixels per image
#define PPT     2                   // pixels per thread (1 packed pair)
#define EPS     1e-5f
#define LOG2E   1.44269504088896340736f

typedef float v2f __attribute__((ext_vector_type(2)));

// Fully fused: per-block gaussian precompute -> LDS, then per-pixel loop.
// Packed per gaussian: A=(mx,my,mz,sg), B=(r,g,b,e0) with
//   kg2 = -0.5*log2e/(sigma^2+eps), sg = sqrt(-kg2), e0 = kg2*|m-o|^2
// Per-pixel rays pre-scaled by sp = sqrt(-(|d|^2-2)) so that
//   arg = e0 + (t*sg)^2  (exp2 domain). The two pixels of a thread are one
//   v2f so the backend emits v_pk_fma_f32 / v_pk_mul_f32 (double-rate fp32).
__global__ __launch_bounds__(256, 8) void render_kernel(
        const float* __restrict__ means,
        const float* __restrict__ covs,
        const float* __restrict__ colors,
        const float* __restrict__ intr,
        const float* __restrict__ extr,
        const int*   __restrict__ img_ids,
        float4*      __restrict__ partial) {  // [SPLIT][n_imgs*NPIX]
    __shared__ float4 sA[GPS];
    __shared__ float4 sB[GPS];

    const int tid   = threadIdx.x;
    const int split = blockIdx.y;
    const int img   = blockIdx.z;
    const int n_imgs = gridDim.z;

    const int cam = img_ids[img];
    const float* E = extr + 16 * cam;
    const float ox = E[3], oy = E[7], oz = E[11];

    if (tid < GPS) {
        const int g = split * GPS + tid;
        const float mx = means[3 * g + 0];
        const float my = means[3 * g + 1];
        const float mz = means[3 * g + 2];
        const float* c = covs + 9 * g;
        const float s2  = (c[0] + c[4] + c[8]) * (1.0f / 3.0f);
        const float sig = sqrtf(s2);                // match reference rounding
        const float kg2 = -0.5f * LOG2E / (sig * sig + EPS);
        const float sg  = sqrtf(-kg2);
        const float ux = mx - ox, uy = my - oy, uz = mz - oz;
        const float e0 = kg2 * (ux * ux + uy * uy + uz * uz);
        sA[tid] = make_float4(mx, my, mz, sg);
        sB[tid] = make_float4(colors[3 * g + 0], colors[3 * g + 1],
                              colors[3 * g + 2], e0);
    }

    const float* I = intr + 4 * cam;
    const float fx = I[0], fy = I[1], cx = I[2], cy = I[3];

    v2f rx, ry, rz, md;
    int pix[PPT];
    #pragma unroll
    for (int p = 0; p < PPT; p++) {
        pix[p] = blockIdx.x * 256 + tid + p * (NPIX / PPT);
        const int row = pix[p] >> 6;
        const int col = pix[p] & 63;
        const float d0 = ((float)col - cx) / fx;
        const float d1 = -(((float)row) - cy) / fy;
        const float d2 = -1.0f;
        const float x = d0 * E[0] + d1 * E[1] + d2 * E[2];
        const float y = d0 * E[4] + d1 * E[5] + d2 * E[6];
        const float z = d0 * E[8] + d1 * E[9] + d2 * E[10];
        const float dd2 = x * x + y * y + z * z - 2.0f;   // < 0 for this setup
        const float sp  = sqrtf(-dd2);
        rx[p] = x * sp;
        ry[p] = y * sp;
        rz[p] = z * sp;
        md[p] = -(ox * x + oy * y + oz * z) * sp;
    }

    __syncthreads();

    v2f wv = {0.f, 0.f}, rv = {0.f, 0.f}, gv = {0.f, 0.f}, bv = {0.f, 0.f};

    #pragma unroll 8
    for (int g = 0; g < GPS; g++) {
        const float4 a = sA[g];
        const float4 b = sB[g];
        const v2f ax = {a.x, a.x}, ay = {a.y, a.y}, az = {a.z, a.z};
        const v2f sgv = {a.w, a.w};
        const v2f e0v = {b.w, b.w};
        const v2f bxx = {b.x, b.x}, byy = {b.y, b.y}, bzz = {b.z, b.z};
        const v2f t = __builtin_elementwise_fma(ax, rx,
                      __builtin_elementwise_fma(ay, ry,
                      __builtin_elementwise_fma(az, rz, md)));
        const v2f u = t * sgv;
        const v2f arg = __builtin_elementwise_fma(u, u, e0v);
        v2f e;
        e.x = __builtin_amdgcn_exp2f(arg.x);
        e.y = __builtin_amdgcn_exp2f(arg.y);
        wv += e;
        rv = __builtin_elementwise_fma(e, bxx, rv);
        gv = __builtin_elementwise_fma(e, byy, gv);
        bv = __builtin_elementwise_fma(e, bzz, bv);
    }

    const int stride = n_imgs * NPIX;
    float4* P = partial + (size_t)split * stride + img * NPIX;
    P[pix[0]] = make_float4(wv.x, rv.x, gv.x, bv.x);
    P[pix[1]] = make_float4(wv.y, rv.y, gv.y, bv.y);
}

__global__ void reduce_kernel(const float4* __restrict__ partial,
                              float* __restrict__ out,
                              int n_imgs) {
    const int idx = blockIdx.x * blockDim.x + threadIdx.x;
    const int total = n_imgs * NPIX;
    if (idx >= total) return;
    float w = 0.0f, r = 0.0f, g = 0.0f, b = 0.0f;
    #pragma unroll 8
    for (int s = 0; s < SPLIT; s++) {
        const float4 p = partial[(size_t)s * total + idx];
        w += p.x; r += p.y; g += p.z; b += p.w;
    }
    const float inv = 1.0f / (w + EPS);
    const int img = idx >> 12;        // / NPIX
    const int pix = idx & (NPIX - 1);
    out[(img * 3 + 0) * NPIX + pix] = r * inv;
    out[(img * 3 + 1) * NPIX + pix] = g * inv;
    out[(img * 3 + 2) * NPIX + pix] = b * inv;
}

extern "C" void kernel_launch(void* const* d_in, const int* in_sizes, int n_in,
                              void* d_out, int out_size, void* d_ws, size_t ws_size,
                              hipStream_t stream) {
    const float* means   = (const float*)d_in[0];
    const float* covs    = (const float*)d_in[1];
    const float* colors  = (const float*)d_in[2];
    const float* intr    = (const float*)d_in[3];
    const float* extr    = (const float*)d_in[4];
    const int*   img_ids = (const int*)d_in[5];
    float* out = (float*)d_out;
    const int n_imgs = in_sizes[5];

    float4* partial = (float4*)d_ws;   // SPLIT * n_imgs * NPIX float4s

    dim3 grid(NPIX / (256 * PPT), SPLIT, n_imgs);
    render_kernel<<<grid, 256, 0, stream>>>(means, covs, colors, intr, extr,
                                            img_ids, partial);

    const int total = n_imgs * NPIX;
    reduce_kernel<<<(total + 255) / 256, 256, 0, stream>>>(partial, out, n_imgs);
}

// Round 9
// 101.921 us; speedup vs baseline: 1.4570x; 1.0133x over previous
//
#include <hip/hip_runtime.h>

#define N_GAUSS 16384
#define SPLIT   128
#define GPS     (N_GAUSS / SPLIT)   // 128 gaussians per block slice
#define GPAIRS  (GPS / 2)           // 64 gaussian pairs
#define TILE    64
#define NPIX    (TILE * TILE)       // 4096 pixels per image
#define PPT     2                   // pixels per thread
#define EPS     1e-5f
#define LOG2E   1.44269504088896340736f

typedef float v2f __attribute__((ext_vector_type(2)));

// Gaussian-dim packing: each v2f lane holds (gaussian 2k, gaussian 2k+1) for
// ONE pixel. Gaussian constants are stored pre-paired in LDS so ds_read_b128
// yields packed operands directly (no per-iteration splat movs); per-pixel ray
// splats are loop-invariant. Accumulators pack over gaussians; halves summed
// in the epilogue.
//   kg2 = -0.5*log2e/(sigma^2+eps), sg = sqrt(-kg2), e0 = kg2*|m-o|^2
//   arg = e0 + (t*sg)^2, rays pre-scaled by sp = sqrt(-(|d|^2-2))
__global__ __launch_bounds__(256, 8) void render_kernel(
        const float* __restrict__ means,
        const float* __restrict__ covs,
        const float* __restrict__ colors,
        const float* __restrict__ intr,
        const float* __restrict__ extr,
        const int*   __restrict__ img_ids,
        float4*      __restrict__ partial) {  // [SPLIT][n_imgs*NPIX]
    // per pair k: [0]={mx0,mx1,my0,my1} [1]={mz0,mz1,sg0,sg1}
    //             [2]={r0,r1,g0,g1}     [3]={b0,b1,e00,e01}
    __shared__ float4 sG[GPAIRS][4];

    const int tid   = threadIdx.x;
    const int split = blockIdx.y;
    const int img   = blockIdx.z;
    const int n_imgs = gridDim.z;

    const int cam = img_ids[img];
    const float* E = extr + 16 * cam;
    const float ox = E[3], oy = E[7], oz = E[11];

    if (tid < GPAIRS) {
        const int g0 = split * GPS + 2 * tid;
        float mx[2], my[2], mz[2], sg[2], e0[2], cr[2], cg[2], cb[2];
        #pragma unroll
        for (int j = 0; j < 2; j++) {
            const int g = g0 + j;
            mx[j] = means[3 * g + 0];
            my[j] = means[3 * g + 1];
            mz[j] = means[3 * g + 2];
            const float* c = covs + 9 * g;
            const float s2  = (c[0] + c[4] + c[8]) * (1.0f / 3.0f);
            const float sig = sqrtf(s2);            // match reference rounding
            const float kg2 = -0.5f * LOG2E / (sig * sig + EPS);
            sg[j] = sqrtf(-kg2);
            const float ux = mx[j] - ox, uy = my[j] - oy, uz = mz[j] - oz;
            e0[j] = kg2 * (ux * ux + uy * uy + uz * uz);
            cr[j] = colors[3 * g + 0];
            cg[j] = colors[3 * g + 1];
            cb[j] = colors[3 * g + 2];
        }
        sG[tid][0] = make_float4(mx[0], mx[1], my[0], my[1]);
        sG[tid][1] = make_float4(mz[0], mz[1], sg[0], sg[1]);
        sG[tid][2] = make_float4(cr[0], cr[1], cg[0], cg[1]);
        sG[tid][3] = make_float4(cb[0], cb[1], e0[0], e0[1]);
    }

    const float* I = intr + 4 * cam;
    const float fx = I[0], fy = I[1], cx = I[2], cy = I[3];

    // loop-invariant packed ray splats, one per pixel
    v2f rxs[PPT], rys[PPT], rzs[PPT], mds[PPT];
    int pix[PPT];
    #pragma unroll
    for (int p = 0; p < PPT; p++) {
        pix[p] = blockIdx.x * 256 + tid + p * (NPIX / PPT);
        const int row = pix[p] >> 6;
        const int col = pix[p] & 63;
        const float d0 = ((float)col - cx) / fx;
        const float d1 = -(((float)row) - cy) / fy;
        const float d2 = -1.0f;
        const float x = d0 * E[0] + d1 * E[1] + d2 * E[2];
        const float y = d0 * E[4] + d1 * E[5] + d2 * E[6];
        const float z = d0 * E[8] + d1 * E[9] + d2 * E[10];
        const float dd2 = x * x + y * y + z * z - 2.0f;   // < 0 for this setup
        const float sp  = sqrtf(-dd2);
        const float vx = x * sp, vy = y * sp, vz = z * sp;
        const float vm = -(ox * x + oy * y + oz * z) * sp;
        rxs[p] = (v2f){vx, vx};
        rys[p] = (v2f){vy, vy};
        rzs[p] = (v2f){vz, vz};
        mds[p] = (v2f){vm, vm};
    }

    __syncthreads();

    v2f wv[PPT], rv[PPT], gv[PPT], bv[PPT];
    #pragma unroll
    for (int p = 0; p < PPT; p++) {
        wv[p] = (v2f){0.f, 0.f}; rv[p] = (v2f){0.f, 0.f};
        gv[p] = (v2f){0.f, 0.f}; bv[p] = (v2f){0.f, 0.f};
    }

    #pragma unroll 2
    for (int k = 0; k < GPAIRS; k++) {
        const float4 q0 = sG[k][0];
        const float4 q1 = sG[k][1];
        const float4 q2 = sG[k][2];
        const float4 q3 = sG[k][3];
        const v2f mxp = {q0.x, q0.y}, myp = {q0.z, q0.w};
        const v2f mzp = {q1.x, q1.y}, sgp = {q1.z, q1.w};
        const v2f crp = {q2.x, q2.y}, cgp = {q2.z, q2.w};
        const v2f cbp = {q3.x, q3.y}, e0p = {q3.z, q3.w};
        #pragma unroll
        for (int p = 0; p < PPT; p++) {
            const v2f t = __builtin_elementwise_fma(mxp, rxs[p],
                          __builtin_elementwise_fma(myp, rys[p],
                          __builtin_elementwise_fma(mzp, rzs[p], mds[p])));
            const v2f u = t * sgp;
            const v2f arg = __builtin_elementwise_fma(u, u, e0p);
            v2f e;
            e.x = __builtin_amdgcn_exp2f(arg.x);
            e.y = __builtin_amdgcn_exp2f(arg.y);
            wv[p] += e;
            rv[p] = __builtin_elementwise_fma(e, crp, rv[p]);
            gv[p] = __builtin_elementwise_fma(e, cgp, gv[p]);
            bv[p] = __builtin_elementwise_fma(e, cbp, bv[p]);
        }
    }

    const int stride = n_imgs * NPIX;
    float4* P = partial + (size_t)split * stride + img * NPIX;
    #pragma unroll
    for (int p = 0; p < PPT; p++) {
        P[pix[p]] = make_float4(wv[p].x + wv[p].y, rv[p].x + rv[p].y,
                                gv[p].x + gv[p].y, bv[p].x + bv[p].y);
    }
}

__global__ void reduce_kernel(const float4* __restrict__ partial,
                              float* __restrict__ out,
                              int n_imgs) {
    const int idx = blockIdx.x * blockDim.x + threadIdx.x;
    const int total = n_imgs * NPIX;
    if (idx >= total) return;
    float w = 0.0f, r = 0.0f, g = 0.0f, b = 0.0f;
    #pragma unroll 8
    for (int s = 0; s < SPLIT; s++) {
        const float4 p = partial[(size_t)s * total + idx];
        w += p.x; r += p.y; g += p.z; b += p.w;
    }
    const float inv = 1.0f / (w + EPS);
    const int img = idx >> 12;        // / NPIX
    const int pix = idx & (NPIX - 1);
    out[(img * 3 + 0) * NPIX + pix] = r * inv;
    out[(img * 3 + 1) * NPIX + pix] = g * inv;
    out[(img * 3 + 2) * NPIX + pix] = b * inv;
}

extern "C" void kernel_launch(void* const* d_in, const int* in_sizes, int n_in,
                              void* d_out, int out_size, void* d_ws, size_t ws_size,
                              hipStream_t stream) {
    const float* means   = (const float*)d_in[0];
    const float* covs    = (const float*)d_in[1];
    const float* colors  = (const float*)d_in[2];
    const float* intr    = (const float*)d_in[3];
    const float* extr    = (const float*)d_in[4];
    const int*   img_ids = (const int*)d_in[5];
    float* out = (float*)d_out;
    const int n_imgs = in_sizes[5];

    float4* partial = (float4*)d_ws;   // SPLIT * n_imgs * NPIX float4s

    dim3 grid(NPIX / (256 * PPT), SPLIT, n_imgs);
    render_kernel<<<grid, 256, 0, stream>>>(means, covs, colors, intr, extr,
                                            img_ids, partial);

    const int total = n_imgs * NPIX;
    reduce_kernel<<<(total + 255) / 256, 256, 0, stream>>>(partial, out, n_imgs);
}